// Round 1
// baseline (175.904 us; speedup 1.0000x reference)
//
#include <hip/hip_runtime.h>
#include <math.h>

#define S_N 2048
#define X_N 2048
#define G_N 2
#define F_N 3072

#define TM 128
#define TN 128
#define BK 32

typedef __bf16 bf16;
typedef __bf16 bf16x4 __attribute__((ext_vector_type(4)));
typedef __bf16 bf16x8 __attribute__((ext_vector_type(8)));
typedef float f32x4 __attribute__((ext_vector_type(4)));

// ---------------- P0a: const[g] = -0.5*F*log(2pi) - sum_f log(std[g,f]) ----
__global__ void k_const(const float* __restrict__ stdv, float* __restrict__ constg) {
  int g = blockIdx.x;
  int t = threadIdx.x;
  float s = 0.f;
  for (int f = t; f < F_N; f += 256) s += logf(stdv[g * F_N + f]);
  for (int o = 32; o; o >>= 1) s += __shfl_xor(s, o);
  __shared__ float red[4];
  int w = t >> 6, l = t & 63;
  if (l == 0) red[w] = s;
  __syncthreads();
  if (t == 0) {
    float tot = red[0] + red[1] + red[2] + red[3];
    // log(2*pi) = 1.8378770664093453
    constg[g] = -0.5f * (float)F_N * 1.8378770664093453f - tot;
  }
}

// ---------------- P0b: u = s/std_g (bf16) + A[g,s]=||u||^2 ; same for x->v,C
__global__ void k_prep(const float* __restrict__ samples, const float* __restrict__ xin,
                       const float* __restrict__ stdv,
                       bf16* __restrict__ U, bf16* __restrict__ V,
                       float* __restrict__ A, float* __restrict__ C) {
  int r = blockIdx.x;
  int t = threadIdx.x;
  bool isS = (r < S_N);
  const float* src = isS ? (samples + (size_t)r * F_N) : (xin + (size_t)(r - S_N) * F_N);
  float4 row[3];
#pragma unroll
  for (int j = 0; j < 3; ++j) row[j] = ((const float4*)src)[t + j * 256];

  __shared__ float red[4];
  int w = t >> 6, l = t & 63;

  for (int g = 0; g < G_N; ++g) {
    const float4* sd = (const float4*)(stdv + (size_t)g * F_N);
    bf16* dst = isS ? (U + ((size_t)g * S_N + r) * F_N)
                    : (V + ((size_t)g * X_N + (r - S_N)) * F_N);
    float acc = 0.f;
#pragma unroll
    for (int j = 0; j < 3; ++j) {
      float4 d = sd[t + j * 256];
      float u0 = row[j].x / d.x;
      float u1 = row[j].y / d.y;
      float u2 = row[j].z / d.z;
      float u3 = row[j].w / d.w;
      bf16x4 b;
      b[0] = (bf16)u0; b[1] = (bf16)u1; b[2] = (bf16)u2; b[3] = (bf16)u3;
      float f0 = (float)b[0], f1 = (float)b[1], f2 = (float)b[2], f3 = (float)b[3];
      acc += f0 * f0 + f1 * f1 + f2 * f2 + f3 * f3;
      ((bf16x4*)dst)[t + j * 256] = b;
    }
    for (int o = 32; o; o >>= 1) acc += __shfl_xor(acc, o);
    __syncthreads();  // protect red[] from previous g iteration
    if (l == 0) red[w] = acc;
    __syncthreads();
    if (t == 0) {
      float tot = red[0] + red[1] + red[2] + red[3];
      if (isS) A[(size_t)g * S_N + r] = tot;
      else     C[(size_t)g * X_N + (r - S_N)] = tot;
    }
  }
}

// ---------------- P1: logits[g,s,x] = (u v^T)[s,x] - 0.5*(A[g,s]+C[g,x]) ----
// m97-style: 128x128 block tile, 4 waves (2x2), each wave 4x4 of 16x16x32 bf16
// MFMA. global_load_lds width=16 with XOR chunk swizzle for LDS bank behavior.
__global__ __launch_bounds__(256) void k_gemm(const bf16* __restrict__ U, const bf16* __restrict__ V,
                                              const float* __restrict__ A, const float* __restrict__ C,
                                              float* __restrict__ logits) {
  __shared__ bf16 ldsA[TM * BK];
  __shared__ bf16 ldsB[TN * BK];

  int t = threadIdx.x;
  int g = blockIdx.z;
  int bm = blockIdx.y * TM;
  int bn = blockIdx.x * TN;

  const bf16* Ub = U + ((size_t)g * S_N + bm) * F_N;
  const bf16* Vb = V + ((size_t)g * X_N + bn) * F_N;

  int wave = t >> 6, lane = t & 63;
  int wm = wave & 1, wn = wave >> 1;
  int r = lane & 15, q = lane >> 4;
  int sq = q ^ (r & 3);  // read-side swizzled k-chunk

  // Staging: 512 16B chunks per tile; thread t handles chunks t and t+256.
  // LDS slot (row, cc) holds global chunk (row, cc ^ (row&3)).
  int c0 = t, c1 = t + 256;
  int row0 = c0 >> 2, gc0 = (c0 & 3) ^ (row0 & 3);
  int row1 = c1 >> 2, gc1 = (c1 & 3) ^ (row1 & 3);
  const bf16* gA0 = Ub + (size_t)row0 * F_N + gc0 * 8;
  const bf16* gA1 = Ub + (size_t)row1 * F_N + gc1 * 8;
  const bf16* gB0 = Vb + (size_t)row0 * F_N + gc0 * 8;
  const bf16* gB1 = Vb + (size_t)row1 * F_N + gc1 * 8;
  bf16* lA0 = ldsA + c0 * 8;
  bf16* lA1 = ldsA + c1 * 8;
  bf16* lB0 = ldsB + c0 * 8;
  bf16* lB1 = ldsB + c1 * 8;

  f32x4 acc[4][4] = {};

  int abase = (wm * 64 + r) * BK + sq * 8;
  int bbase = (wn * 64 + r) * BK + sq * 8;

  for (int k0 = 0; k0 < F_N; k0 += BK) {
    __syncthreads();  // previous iteration's LDS reads done
    __builtin_amdgcn_global_load_lds((const __attribute__((address_space(1))) void*)(gA0 + k0),
                                     (__attribute__((address_space(3))) void*)lA0, 16, 0, 0);
    __builtin_amdgcn_global_load_lds((const __attribute__((address_space(1))) void*)(gA1 + k0),
                                     (__attribute__((address_space(3))) void*)lA1, 16, 0, 0);
    __builtin_amdgcn_global_load_lds((const __attribute__((address_space(1))) void*)(gB0 + k0),
                                     (__attribute__((address_space(3))) void*)lB0, 16, 0, 0);
    __builtin_amdgcn_global_load_lds((const __attribute__((address_space(1))) void*)(gB1 + k0),
                                     (__attribute__((address_space(3))) void*)lB1, 16, 0, 0);
    __syncthreads();  // waits vmcnt(0): staged data visible

    bf16x8 af[4], bfr[4];
#pragma unroll
    for (int mi = 0; mi < 4; ++mi) af[mi] = *(const bf16x8*)(ldsA + abase + mi * 16 * BK);
#pragma unroll
    for (int ni = 0; ni < 4; ++ni) bfr[ni] = *(const bf16x8*)(ldsB + bbase + ni * 16 * BK);

#pragma unroll
    for (int mi = 0; mi < 4; ++mi)
#pragma unroll
      for (int ni = 0; ni < 4; ++ni)
        acc[mi][ni] = __builtin_amdgcn_mfma_f32_16x16x32_bf16(af[mi], bfr[ni], acc[mi][ni], 0, 0, 0);
  }

  // Epilogue: C/D layout col=lane&15, row=(lane>>4)*4+reg
  const float* Ap = A + (size_t)g * S_N + bm + wm * 64;
  const float* Cp = C + (size_t)g * X_N + bn + wn * 64;
  float cv[4];
#pragma unroll
  for (int ni = 0; ni < 4; ++ni) cv[ni] = Cp[ni * 16 + r];
#pragma unroll
  for (int mi = 0; mi < 4; ++mi) {
#pragma unroll
    for (int i = 0; i < 4; ++i) {
      int rowl = wm * 64 + mi * 16 + q * 4 + i;
      float av = Ap[mi * 16 + q * 4 + i];
      float* orow = logits + ((size_t)g * S_N + bm + rowl) * X_N + bn + wn * 64;
#pragma unroll
      for (int ni = 0; ni < 4; ++ni)
        orow[ni * 16 + r] = acc[mi][ni][i] - 0.5f * (av + cv[ni]);
    }
  }
}

// ---------------- P2: out[s] = LSE over (g,x) of (logits + const[g]) - log(X*G)
__global__ void k_lse(const float* __restrict__ logits, const float* __restrict__ constg,
                      float* __restrict__ out) {
  int s = blockIdx.x, t = threadIdx.x;
  float c0 = constg[0], c1 = constg[1];
  const float4* p0 = (const float4*)(logits + (size_t)s * X_N);
  const float4* p1 = (const float4*)(logits + ((size_t)S_N + s) * X_N);
  float4 v[4];
  v[0] = p0[t]; v[1] = p0[t + 256];
  v[2] = p1[t]; v[3] = p1[t + 256];
  v[0].x += c0; v[0].y += c0; v[0].z += c0; v[0].w += c0;
  v[1].x += c0; v[1].y += c0; v[1].z += c0; v[1].w += c0;
  v[2].x += c1; v[2].y += c1; v[2].z += c1; v[2].w += c1;
  v[3].x += c1; v[3].y += c1; v[3].z += c1; v[3].w += c1;

  float m = v[0].x;
#pragma unroll
  for (int j = 0; j < 4; ++j) {
    m = fmaxf(m, v[j].x); m = fmaxf(m, v[j].y);
    m = fmaxf(m, v[j].z); m = fmaxf(m, v[j].w);
  }
  for (int o = 32; o; o >>= 1) m = fmaxf(m, __shfl_xor(m, o));
  __shared__ float redm[4];
  __shared__ float reds[4];
  int w = t >> 6, l = t & 63;
  if (l == 0) redm[w] = m;
  __syncthreads();
  m = fmaxf(fmaxf(redm[0], redm[1]), fmaxf(redm[2], redm[3]));

  float sum = 0.f;
#pragma unroll
  for (int j = 0; j < 4; ++j) {
    sum += expf(v[j].x - m) + expf(v[j].y - m) + expf(v[j].z - m) + expf(v[j].w - m);
  }
  for (int o = 32; o; o >>= 1) sum += __shfl_xor(sum, o);
  if (l == 0) reds[w] = sum;
  __syncthreads();
  if (t == 0) {
    float tot = reds[0] + reds[1] + reds[2] + reds[3];
    // log(X*G) = log(4096)
    out[s] = m + logf(tot) - 8.317766166719343f;
  }
}

extern "C" void kernel_launch(void* const* d_in, const int* in_sizes, int n_in,
                              void* d_out, int out_size, void* d_ws, size_t ws_size,
                              hipStream_t stream) {
  const float* samples = (const float*)d_in[0];  // [S, F] fp32
  const float* xin     = (const float*)d_in[1];  // [X, F] fp32
  const float* stdv    = (const float*)d_in[2];  // [G, F] fp32
  float* out = (float*)d_out;                    // [S] fp32

  char* ws = (char*)d_ws;
  size_t off = 0;
  bf16* U = (bf16*)(ws + off);       off += (size_t)G_N * S_N * F_N * 2;  // 25.2 MB
  bf16* V = (bf16*)(ws + off);       off += (size_t)G_N * X_N * F_N * 2;  // 25.2 MB
  float* logits = (float*)(ws + off); off += (size_t)G_N * S_N * X_N * 4; // 33.6 MB
  float* A = (float*)(ws + off);     off += (size_t)G_N * S_N * 4;
  float* C = (float*)(ws + off);     off += (size_t)G_N * X_N * 4;
  float* constg = (float*)(ws + off); off += 256;

  k_const<<<dim3(G_N), dim3(256), 0, stream>>>(stdv, constg);
  k_prep<<<dim3(S_N + X_N), dim3(256), 0, stream>>>(samples, xin, stdv, U, V, A, C);
  k_gemm<<<dim3(X_N / TN, S_N / TM, G_N), dim3(256), 0, stream>>>(U, V, A, C, logits);
  k_lse<<<dim3(S_N), dim3(256), 0, stream>>>(logits, constg, out);
}